// Round 1
// 1379.721 us; speedup vs baseline: 3.6125x; 3.6125x over previous
//
#include <hip/hip_runtime.h>

#define B_    64
#define C_    512
#define H_    32
#define WDIM  32
#define N_    1024   // H*W
#define M3C   1536   // 3*C
#define LDK   40     // padded LDS row stride (bf16 elems) for 32-wide K tiles

typedef unsigned short ushort_t;
typedef __attribute__((ext_vector_type(8))) short bf16x8;
typedef __attribute__((ext_vector_type(4))) float f32x4;

// ---------------------------------------------------------------------------
// bf16 split helpers (RNE)
// ---------------------------------------------------------------------------
__device__ __forceinline__ ushort_t f2bf(float x) {
    unsigned u = __float_as_uint(x);
    unsigned r = (u + 0x7FFFu + ((u >> 16) & 1u)) >> 16;
    return (ushort_t)r;
}
__device__ __forceinline__ float bf2f(ushort_t b) {
    return __uint_as_float(((unsigned)b) << 16);
}
__device__ __forceinline__ void split_write(float v, ushort_t* __restrict__ ph,
                                            ushort_t* __restrict__ pl, size_t idx) {
    ushort_t hb = f2bf(v);
    ph[idx] = hb;
    pl[idx] = f2bf(v - bf2f(hb));
}

// ---------------------------------------------------------------------------
// W split: W[o][c] fp32 -> hi/lo bf16 planes (same layout, k=c innermost)
// ---------------------------------------------------------------------------
__global__ __launch_bounds__(256) void w_split(const float* __restrict__ W,
                                               ushort_t* __restrict__ Wh,
                                               ushort_t* __restrict__ Wl) {
    int idx = blockIdx.x * 256 + threadIdx.x;
    if (idx >= M3C * C_) return;
    split_write(W[idx], Wh, Wl, idx);
}

// ---------------------------------------------------------------------------
// posT[n][c] = rel_h[c,h] + rel_w[c,w], split hi/lo  (k=c innermost)
// ---------------------------------------------------------------------------
__global__ __launch_bounds__(256) void posT_split(const float* __restrict__ rel_h,
                                                  const float* __restrict__ rel_w,
                                                  ushort_t* __restrict__ ph,
                                                  ushort_t* __restrict__ pl) {
    int idx = blockIdx.x * 256 + threadIdx.x;   // over N_*C_, layout [n][c]
    if (idx >= N_ * C_) return;
    int n = idx >> 9;            // /C_
    int c = idx & (C_ - 1);
    int h = n >> 5, w = n & 31;
    float v = rel_h[c * H_ + h] + rel_w[c * WDIM + w];
    split_write(v, ph, pl, idx);
}

// ---------------------------------------------------------------------------
// xT split: x[bl][c][n] fp32 -> xT hi/lo planes [bl][n][c]  (32x32 LDS transpose)
// ---------------------------------------------------------------------------
__global__ __launch_bounds__(256) void xT_split(const float* __restrict__ x,
                                                ushort_t* __restrict__ xh,
                                                ushort_t* __restrict__ xl) {
    __shared__ float t[32][33];
    const int bl = blockIdx.z;
    const int c0 = blockIdx.y * 32;
    const int n0 = blockIdx.x * 32;
    const float* xb = x + (size_t)bl * C_ * N_;
    ushort_t* xhb = xh + (size_t)bl * N_ * C_;
    ushort_t* xlb = xl + (size_t)bl * N_ * C_;
    const int tx = threadIdx.x & 31, ty = threadIdx.x >> 5;
    #pragma unroll
    for (int r = 0; r < 4; ++r)
        t[ty + r * 8][tx] = xb[(size_t)(c0 + ty + r * 8) * N_ + n0 + tx];
    __syncthreads();
    #pragma unroll
    for (int r = 0; r < 4; ++r) {
        float v = t[tx][ty + r * 8];
        size_t o = (size_t)(n0 + ty + r * 8) * C_ + c0 + tx;
        split_write(v, xhb, xlb, o);
    }
}

// ---------------------------------------------------------------------------
// Stage a 128-row x 32-k bf16 tile (global row stride gstride elems) into LDS
// with padded stride LDK. 16B vector copies; 2 per thread.
// ---------------------------------------------------------------------------
__device__ __forceinline__ void stage128x32(const ushort_t* __restrict__ gsrc, int gstride,
                                            ushort_t* __restrict__ lds, int tid) {
    #pragma unroll
    for (int t = 0; t < 2; ++t) {
        int idx = tid + t * 256;        // 0..511
        int row = idx >> 2;             // 0..127
        int col = (idx & 3) << 3;       // 0,8,16,24
        *reinterpret_cast<int4*>(&lds[row * LDK + col]) =
            *reinterpret_cast<const int4*>(&gsrc[(size_t)row * gstride + col]);
    }
}

// ---------------------------------------------------------------------------
// qkv GEMM (bf16x2 split, 3 MFMA/pair): D[o][n] = sum_c W[o][c] x[c][n]
// A = W hi/lo [o][c]; B^T = xT hi/lo [n][c]. 128x128 tile, 4 waves 2x2.
// Epilogue: o<1024 -> write qkT[n][o] hi/lo (transposed, for s_mfma);
//           o>=1024 -> write v[c][m] hi/lo (natural, for out_mfma).
// ---------------------------------------------------------------------------
__global__ __launch_bounds__(256) void qkv_mfma(const ushort_t* __restrict__ Wh,
                                                const ushort_t* __restrict__ Wl,
                                                const ushort_t* __restrict__ xh,
                                                const ushort_t* __restrict__ xl,
                                                ushort_t* __restrict__ qkTh,
                                                ushort_t* __restrict__ qkTl,
                                                ushort_t* __restrict__ vh,
                                                ushort_t* __restrict__ vl) {
    __shared__ __align__(16) ushort_t lsAh[128 * LDK];
    __shared__ __align__(16) ushort_t lsAl[128 * LDK];
    __shared__ __align__(16) ushort_t lsBh[128 * LDK];
    __shared__ __align__(16) ushort_t lsBl[128 * LDK];
    const int bl = blockIdx.z;
    const int m0 = blockIdx.y * 128;   // o
    const int n0 = blockIdx.x * 128;   // n
    const ushort_t* xhb = xh + (size_t)bl * N_ * C_;
    const ushort_t* xlb = xl + (size_t)bl * N_ * C_;
    const int tid = threadIdx.x;
    const int lane = tid & 63, wid = tid >> 6;
    const int wr = wid >> 1, wc = wid & 1;
    const int lr = lane & 15, g = lane >> 4, g8 = g << 3;
    f32x4 acc[4][4] = {};
    for (int k0 = 0; k0 < C_; k0 += 32) {
        stage128x32(Wh + (size_t)m0 * C_ + k0, C_, lsAh, tid);
        stage128x32(Wl + (size_t)m0 * C_ + k0, C_, lsAl, tid);
        stage128x32(xhb + (size_t)n0 * C_ + k0, C_, lsBh, tid);
        stage128x32(xlb + (size_t)n0 * C_ + k0, C_, lsBl, tid);
        __syncthreads();
        bf16x8 a_h[4], a_l[4], b_h[4], b_l[4];
        #pragma unroll
        for (int i = 0; i < 4; ++i) {
            int ra = (wr * 64 + i * 16 + lr) * LDK + g8;
            int rb = (wc * 64 + i * 16 + lr) * LDK + g8;
            a_h[i] = *reinterpret_cast<const bf16x8*>(&lsAh[ra]);
            a_l[i] = *reinterpret_cast<const bf16x8*>(&lsAl[ra]);
            b_h[i] = *reinterpret_cast<const bf16x8*>(&lsBh[rb]);
            b_l[i] = *reinterpret_cast<const bf16x8*>(&lsBl[rb]);
        }
        #pragma unroll
        for (int i = 0; i < 4; ++i)
            #pragma unroll
            for (int j = 0; j < 4; ++j) {
                acc[i][j] = __builtin_amdgcn_mfma_f32_16x16x32_bf16(a_h[i], b_h[j], acc[i][j], 0, 0, 0);
                acc[i][j] = __builtin_amdgcn_mfma_f32_16x16x32_bf16(a_h[i], b_l[j], acc[i][j], 0, 0, 0);
                acc[i][j] = __builtin_amdgcn_mfma_f32_16x16x32_bf16(a_l[i], b_h[j], acc[i][j], 0, 0, 0);
            }
        __syncthreads();
    }
    if (m0 < 2 * C_) {
        // q / k region: write transposed split planes qkT[n][o]
        ushort_t* qh = qkTh + (size_t)bl * N_ * 1024;
        ushort_t* ql = qkTl + (size_t)bl * N_ * 1024;
        #pragma unroll
        for (int i = 0; i < 4; ++i) {
            int o = m0 + wr * 64 + i * 16 + g * 4;
            #pragma unroll
            for (int j = 0; j < 4; ++j) {
                int n = n0 + wc * 64 + j * 16 + lr;
                ushort4 h4, l4;
                ushort_t hb;
                float v0 = acc[i][j][0], v1 = acc[i][j][1], v2 = acc[i][j][2], v3 = acc[i][j][3];
                hb = f2bf(v0); h4.x = hb; l4.x = f2bf(v0 - bf2f(hb));
                hb = f2bf(v1); h4.y = hb; l4.y = f2bf(v1 - bf2f(hb));
                hb = f2bf(v2); h4.z = hb; l4.z = f2bf(v2 - bf2f(hb));
                hb = f2bf(v3); h4.w = hb; l4.w = f2bf(v3 - bf2f(hb));
                *reinterpret_cast<ushort4*>(&qh[(size_t)n * 1024 + o]) = h4;
                *reinterpret_cast<ushort4*>(&ql[(size_t)n * 1024 + o]) = l4;
            }
        }
    } else {
        // v region: write natural split planes v[c][m]
        ushort_t* vhb = vh + (size_t)bl * C_ * N_;
        ushort_t* vlb = vl + (size_t)bl * C_ * N_;
        #pragma unroll
        for (int i = 0; i < 4; ++i) {
            int cb = m0 - 2 * C_ + wr * 64 + i * 16 + g * 4;
            #pragma unroll
            for (int j = 0; j < 4; ++j) {
                int n = n0 + wc * 64 + j * 16 + lr;
                #pragma unroll
                for (int r = 0; r < 4; ++r) {
                    float v = acc[i][j][r];
                    ushort_t hb = f2bf(v);
                    vhb[(size_t)(cb + r) * N_ + n] = hb;
                    vlb[(size_t)(cb + r) * N_ + n] = f2bf(v - bf2f(hb));
                }
            }
        }
    }
}

// ---------------------------------------------------------------------------
// S GEMM (bf16x2, 3 MFMA/pair): S[n][m] = sum_c q[c][n]k[c][m] + pos[c][n]q[c][m]
// A = qT/posT [n][c] hi/lo; B^T = kT/qT [m][c] hi/lo. K = 1024 (two segments).
// ---------------------------------------------------------------------------
__global__ __launch_bounds__(256) void s_mfma(const ushort_t* __restrict__ qkTh,
                                              const ushort_t* __restrict__ qkTl,
                                              const ushort_t* __restrict__ posTh,
                                              const ushort_t* __restrict__ posTl,
                                              float* __restrict__ S) {
    __shared__ __align__(16) ushort_t lsAh[128 * LDK];
    __shared__ __align__(16) ushort_t lsAl[128 * LDK];
    __shared__ __align__(16) ushort_t lsBh[128 * LDK];
    __shared__ __align__(16) ushort_t lsBl[128 * LDK];
    const int bl = blockIdx.z;
    const int m0 = blockIdx.x * 128;
    const int n0 = blockIdx.y * 128;
    const ushort_t* qh = qkTh + (size_t)bl * N_ * 1024;
    const ushort_t* ql = qkTl + (size_t)bl * N_ * 1024;
    float* Sb = S + (size_t)bl * N_ * N_;
    const int tid = threadIdx.x;
    const int lane = tid & 63, wid = tid >> 6;
    const int wr = wid >> 1, wc = wid & 1;
    const int lr = lane & 15, g = lane >> 4, g8 = g << 3;
    f32x4 acc[4][4] = {};
    for (int k0 = 0; k0 < 2 * C_; k0 += 32) {
        const ushort_t *Ah, *Al, *Bh, *Bl;
        int As, Bs;
        if (k0 < C_) {
            Ah = qh + (size_t)n0 * 1024 + k0;          As = 1024;
            Al = ql + (size_t)n0 * 1024 + k0;
            Bh = qh + (size_t)m0 * 1024 + C_ + k0;     Bs = 1024;
            Bl = ql + (size_t)m0 * 1024 + C_ + k0;
        } else {
            Ah = posTh + (size_t)n0 * C_ + (k0 - C_);  As = C_;
            Al = posTl + (size_t)n0 * C_ + (k0 - C_);
            Bh = qh + (size_t)m0 * 1024 + (k0 - C_);   Bs = 1024;
            Bl = ql + (size_t)m0 * 1024 + (k0 - C_);
        }
        stage128x32(Ah, As, lsAh, tid);
        stage128x32(Al, As, lsAl, tid);
        stage128x32(Bh, Bs, lsBh, tid);
        stage128x32(Bl, Bs, lsBl, tid);
        __syncthreads();
        bf16x8 a_h[4], a_l[4], b_h[4], b_l[4];
        #pragma unroll
        for (int i = 0; i < 4; ++i) {
            int ra = (wr * 64 + i * 16 + lr) * LDK + g8;
            int rb = (wc * 64 + i * 16 + lr) * LDK + g8;
            a_h[i] = *reinterpret_cast<const bf16x8*>(&lsAh[ra]);
            a_l[i] = *reinterpret_cast<const bf16x8*>(&lsAl[ra]);
            b_h[i] = *reinterpret_cast<const bf16x8*>(&lsBh[rb]);
            b_l[i] = *reinterpret_cast<const bf16x8*>(&lsBl[rb]);
        }
        #pragma unroll
        for (int i = 0; i < 4; ++i)
            #pragma unroll
            for (int j = 0; j < 4; ++j) {
                acc[i][j] = __builtin_amdgcn_mfma_f32_16x16x32_bf16(a_h[i], b_h[j], acc[i][j], 0, 0, 0);
                acc[i][j] = __builtin_amdgcn_mfma_f32_16x16x32_bf16(a_h[i], b_l[j], acc[i][j], 0, 0, 0);
                acc[i][j] = __builtin_amdgcn_mfma_f32_16x16x32_bf16(a_l[i], b_h[j], acc[i][j], 0, 0, 0);
            }
        __syncthreads();
    }
    #pragma unroll
    for (int i = 0; i < 4; ++i) {
        int n = n0 + wr * 64 + i * 16 + g * 4;
        #pragma unroll
        for (int j = 0; j < 4; ++j) {
            int m = m0 + wc * 64 + j * 16 + lr;
            #pragma unroll
            for (int r = 0; r < 4; ++r)
                Sb[(size_t)(n + r) * N_ + m] = acc[i][j][r];
        }
    }
}

// ---------------------------------------------------------------------------
// Row softmax (fp32 in) -> P bf16 [n][m]
// ---------------------------------------------------------------------------
__device__ __forceinline__ float waveMax(float v) {
    #pragma unroll
    for (int o = 32; o > 0; o >>= 1) v = fmaxf(v, __shfl_down(v, o));
    return v;
}
__device__ __forceinline__ float waveSum(float v) {
    #pragma unroll
    for (int o = 32; o > 0; o >>= 1) v += __shfl_down(v, o);
    return v;
}

__global__ __launch_bounds__(256) void softmax_bf16(const float* __restrict__ S,
                                                    ushort_t* __restrict__ P) {
    const float* Sr = S + (size_t)blockIdx.x * N_;
    ushort_t* Pr = P + (size_t)blockIdx.x * N_;
    const int tid = threadIdx.x;
    float4 v = reinterpret_cast<const float4*>(Sr)[tid];
    __shared__ float redm[4];
    __shared__ float reds[4];
    const int wave = tid >> 6, lane = tid & 63;

    float m = fmaxf(fmaxf(v.x, v.y), fmaxf(v.z, v.w));
    m = waveMax(m);
    if (lane == 0) redm[wave] = m;
    __syncthreads();
    m = fmaxf(fmaxf(redm[0], redm[1]), fmaxf(redm[2], redm[3]));

    v.x = __expf(v.x - m); v.y = __expf(v.y - m);
    v.z = __expf(v.z - m); v.w = __expf(v.w - m);
    float s = v.x + v.y + v.z + v.w;
    s = waveSum(s);
    if (lane == 0) reds[wave] = s;
    __syncthreads();
    s = reds[0] + reds[1] + reds[2] + reds[3];
    const float inv = 1.0f / s;
    ushort4 p;
    p.x = f2bf(v.x * inv); p.y = f2bf(v.y * inv);
    p.z = f2bf(v.z * inv); p.w = f2bf(v.w * inv);
    reinterpret_cast<ushort4*>(Pr)[tid] = p;
}

// ---------------------------------------------------------------------------
// out GEMM (v split x2, P single bf16 -> 2 MFMA/pair):
// out[c][n] = sum_m v[c][m] P[n][m].  A = v hi/lo [c][m]; B^T = P [n][m].
// ---------------------------------------------------------------------------
__global__ __launch_bounds__(256) void out_mfma(const ushort_t* __restrict__ vh,
                                                const ushort_t* __restrict__ vl,
                                                const ushort_t* __restrict__ P,
                                                float* __restrict__ out) {
    __shared__ __align__(16) ushort_t lsAh[128 * LDK];
    __shared__ __align__(16) ushort_t lsAl[128 * LDK];
    __shared__ __align__(16) ushort_t lsB[128 * LDK];
    const int bl = blockIdx.z;
    const int c0 = blockIdx.y * 128;
    const int n0 = blockIdx.x * 128;
    const ushort_t* vhb = vh + (size_t)bl * C_ * N_;
    const ushort_t* vlb = vl + (size_t)bl * C_ * N_;
    const ushort_t* Pb  = P + (size_t)bl * N_ * N_;
    float* outb = out + (size_t)bl * C_ * N_;
    const int tid = threadIdx.x;
    const int lane = tid & 63, wid = tid >> 6;
    const int wr = wid >> 1, wc = wid & 1;
    const int lr = lane & 15, g = lane >> 4, g8 = g << 3;
    f32x4 acc[4][4] = {};
    for (int k0 = 0; k0 < N_; k0 += 32) {
        stage128x32(vhb + (size_t)c0 * N_ + k0, N_, lsAh, tid);
        stage128x32(vlb + (size_t)c0 * N_ + k0, N_, lsAl, tid);
        stage128x32(Pb + (size_t)n0 * N_ + k0, N_, lsB, tid);
        __syncthreads();
        bf16x8 a_h[4], a_l[4], b_[4];
        #pragma unroll
        for (int i = 0; i < 4; ++i) {
            int ra = (wr * 64 + i * 16 + lr) * LDK + g8;
            int rb = (wc * 64 + i * 16 + lr) * LDK + g8;
            a_h[i] = *reinterpret_cast<const bf16x8*>(&lsAh[ra]);
            a_l[i] = *reinterpret_cast<const bf16x8*>(&lsAl[ra]);
            b_[i]  = *reinterpret_cast<const bf16x8*>(&lsB[rb]);
        }
        #pragma unroll
        for (int i = 0; i < 4; ++i)
            #pragma unroll
            for (int j = 0; j < 4; ++j) {
                acc[i][j] = __builtin_amdgcn_mfma_f32_16x16x32_bf16(a_h[i], b_[j], acc[i][j], 0, 0, 0);
                acc[i][j] = __builtin_amdgcn_mfma_f32_16x16x32_bf16(a_l[i], b_[j], acc[i][j], 0, 0, 0);
            }
        __syncthreads();
    }
    #pragma unroll
    for (int i = 0; i < 4; ++i) {
        int c = c0 + wr * 64 + i * 16 + g * 4;
        #pragma unroll
        for (int j = 0; j < 4; ++j) {
            int n = n0 + wc * 64 + j * 16 + lr;
            #pragma unroll
            for (int r = 0; r < 4; ++r)
                outb[(size_t)(c + r) * N_ + n] = acc[i][j][r];
        }
    }
}

// ---------------------------------------------------------------------------
extern "C" void kernel_launch(void* const* d_in, const int* in_sizes, int n_in,
                              void* d_out, int out_size, void* d_ws, size_t ws_size,
                              hipStream_t stream) {
    const float* x     = (const float*)d_in[0];
    const float* Wm    = (const float*)d_in[1];
    const float* rel_h = (const float*)d_in[2];
    const float* rel_w = (const float*)d_in[3];
    float* out = (float*)d_out;

    // Workspace layout (bf16 planes except S):
    //   persistent: Wh/Wl (1.5MB each), posTh/posTl (1MB each)        = 5 MiB
    //   per batch:  xTh/xTl (1MB each), qkTh/qkTl (2MB each),
    //               vh/vl (1MB each), S fp32 (4MB), P bf16 (2MB)      = 14 MiB
    const size_t w_plane   = (size_t)M3C * C_ * 2;
    const size_t pos_plane = (size_t)N_ * C_ * 2;
    const size_t xt_plane  = (size_t)N_ * C_ * 2;
    const size_t qkt_plane = (size_t)N_ * 1024 * 2;
    const size_t v_plane   = (size_t)C_ * N_ * 2;
    const size_t s_bytes   = (size_t)N_ * N_ * 4;
    const size_t p_bytes   = (size_t)N_ * N_ * 2;
    const size_t per_batch = 2 * xt_plane + 2 * qkt_plane + 2 * v_plane + s_bytes + p_bytes;
    const size_t persist   = 2 * w_plane + 2 * pos_plane;

    size_t rem = (ws_size > persist) ? (ws_size - persist) : 0;
    int chunkB = (int)(rem / per_batch);
    if (chunkB < 1)  chunkB = 1;
    if (chunkB > B_) chunkB = B_;

    char* p = (char*)d_ws;
    ushort_t* Wh    = (ushort_t*)p; p += w_plane;
    ushort_t* Wl    = (ushort_t*)p; p += w_plane;
    ushort_t* posTh = (ushort_t*)p; p += pos_plane;
    ushort_t* posTl = (ushort_t*)p; p += pos_plane;
    ushort_t* xTh   = (ushort_t*)p; p += (size_t)chunkB * xt_plane;
    ushort_t* xTl   = (ushort_t*)p; p += (size_t)chunkB * xt_plane;
    ushort_t* qkTh  = (ushort_t*)p; p += (size_t)chunkB * qkt_plane;
    ushort_t* qkTl  = (ushort_t*)p; p += (size_t)chunkB * qkt_plane;
    ushort_t* vh    = (ushort_t*)p; p += (size_t)chunkB * v_plane;
    ushort_t* vl    = (ushort_t*)p; p += (size_t)chunkB * v_plane;
    float*    S     = (float*)p;    p += (size_t)chunkB * s_bytes;
    ushort_t* P     = (ushort_t*)p; p += (size_t)chunkB * p_bytes;

    w_split<<<(M3C * C_ + 255) / 256, 256, 0, stream>>>(Wm, Wh, Wl);
    posT_split<<<(N_ * C_ + 255) / 256, 256, 0, stream>>>(rel_h, rel_w, posTh, posTl);

    for (int b0 = 0; b0 < B_; b0 += chunkB) {
        int nb = (b0 + chunkB <= B_) ? chunkB : (B_ - b0);
        const float* x_b   = x   + (size_t)b0 * C_ * N_;
        float*       out_b = out + (size_t)b0 * C_ * N_;
        xT_split<<<dim3(N_ / 32, C_ / 32, nb), 256, 0, stream>>>(x_b, xTh, xTl);
        qkv_mfma<<<dim3(N_ / 128, M3C / 128, nb), 256, 0, stream>>>(Wh, Wl, xTh, xTl,
                                                                    qkTh, qkTl, vh, vl);
        s_mfma<<<dim3(N_ / 128, N_ / 128, nb), 256, 0, stream>>>(qkTh, qkTl, posTh, posTl, S);
        softmax_bf16<<<nb * N_, 256, 0, stream>>>(S, P);
        out_mfma<<<dim3(N_ / 128, C_ / 128, nb), 256, 0, stream>>>(vh, vl, P, out_b);
    }
}

// Round 2
// 1261.249 us; speedup vs baseline: 3.9518x; 1.0939x over previous
//
#include <hip/hip_runtime.h>

#define B_    64
#define C_    512
#define H_    32
#define WDIM  32
#define N_    1024   // H*W
#define M3C   1536   // 3*C

typedef unsigned short ushort_t;
typedef __attribute__((ext_vector_type(8))) short bf16x8;
typedef __attribute__((ext_vector_type(4))) float f32x4;

// ---------------------------------------------------------------------------
// bf16 split helpers (RNE)
// ---------------------------------------------------------------------------
__device__ __forceinline__ ushort_t f2bf(float x) {
    unsigned u = __float_as_uint(x);
    unsigned r = (u + 0x7FFFu + ((u >> 16) & 1u)) >> 16;
    return (ushort_t)r;
}
__device__ __forceinline__ float bf2f(ushort_t b) {
    return __uint_as_float(((unsigned)b) << 16);
}
__device__ __forceinline__ void split_write(float v, ushort_t* __restrict__ ph,
                                            ushort_t* __restrict__ pl, size_t idx) {
    ushort_t hb = f2bf(v);
    ph[idx] = hb;
    pl[idx] = f2bf(v - bf2f(hb));
}

// async global->LDS, 16B per lane (dst = wave-uniform base + lane*16)
__device__ __forceinline__ void gld16(const void* g, void* l) {
    __builtin_amdgcn_global_load_lds((const __attribute__((address_space(1))) unsigned int*)g,
                                     (__attribute__((address_space(3))) unsigned int*)l,
                                     16, 0, 0);
}

// ---------------------------------------------------------------------------
// pos[c, h*W+w] = rel_h[c,h] + rel_w[c,w]   (fp32)
// ---------------------------------------------------------------------------
__global__ __launch_bounds__(256) void pos_kernel(const float* __restrict__ rel_h,
                                                  const float* __restrict__ rel_w,
                                                  float* __restrict__ pos) {
    int idx = blockIdx.x * 256 + threadIdx.x;
    if (idx >= C_ * N_) return;
    int c = idx >> 10;
    int n = idx & (N_ - 1);
    int h = n >> 5;
    int w = n & (WDIM - 1);
    pos[idx] = rel_h[c * H_ + h] + rel_w[c * WDIM + w];
}

// ---------------------------------------------------------------------------
// fp32 GEMM, both operands k-major: D[m][n] = sum_k A[k][m] * B[k][n]
// (used once for M = Wq^T Wk and r = Wq^T pos; tiny)
// ---------------------------------------------------------------------------
__global__ __launch_bounds__(256) void mmT_f32(const float* __restrict__ A, int lda,
                                               const float* __restrict__ B, int ldb,
                                               float* __restrict__ D, int ldd, int K) {
    __shared__ float As[16][64];
    __shared__ float Bs[16][64];
    const int m0 = blockIdx.y * 64;
    const int n0 = blockIdx.x * 64;
    const int tx = threadIdx.x, ty = threadIdx.y;
    const int tid = ty * 16 + tx;
    float acc[4][4] = {};
    for (int k0 = 0; k0 < K; k0 += 16) {
        #pragma unroll
        for (int t = 0; t < 4; ++t) {
            int e = tid + t * 256;
            int j = e >> 6, i = e & 63;
            As[j][i] = A[(size_t)(k0 + j) * lda + m0 + i];
            Bs[j][i] = B[(size_t)(k0 + j) * ldb + n0 + i];
        }
        __syncthreads();
        #pragma unroll
        for (int kk = 0; kk < 16; ++kk) {
            float a[4], bb[4];
            #pragma unroll
            for (int i = 0; i < 4; ++i) a[i]  = As[kk][ty * 4 + i];
            #pragma unroll
            for (int j = 0; j < 4; ++j) bb[j] = Bs[kk][tx * 4 + j];
            #pragma unroll
            for (int i = 0; i < 4; ++i)
                #pragma unroll
                for (int j = 0; j < 4; ++j)
                    acc[i][j] += a[i] * bb[j];
        }
        __syncthreads();
    }
    #pragma unroll
    for (int i = 0; i < 4; ++i)
        #pragma unroll
        for (int j = 0; j < 4; ++j)
            D[(size_t)(m0 + ty * 4 + i) * ldd + n0 + tx * 4 + j] = acc[i][j];
}

// ---------------------------------------------------------------------------
// F = [M ; Wv] split into bf16 hi/lo planes, natural [o][c] layout (k=c inner)
// ---------------------------------------------------------------------------
__global__ __launch_bounds__(256) void f_split(const float* __restrict__ Mtmp,
                                               const float* __restrict__ Wm,
                                               ushort_t* __restrict__ Fh,
                                               ushort_t* __restrict__ Fl) {
    int idx = blockIdx.x * 256 + threadIdx.x;
    if (idx >= 1024 * C_) return;
    int o = idx >> 9;
    int c = idx & (C_ - 1);
    float v = (o < 512) ? Mtmp[idx] : Wm[(size_t)(512 + o) * C_ + c];
    split_write(v, Fh, Fl, idx);
}

// ---------------------------------------------------------------------------
// transpose+split: src[C_][N_] fp32 -> dst hi/lo planes [N_][C_] bf16
// (used per-batch for x, and once for r)
// ---------------------------------------------------------------------------
__global__ __launch_bounds__(256) void xT_split(const float* __restrict__ x,
                                                ushort_t* __restrict__ xh,
                                                ushort_t* __restrict__ xl) {
    __shared__ float t[32][33];
    const int bl = blockIdx.z;
    const int c0 = blockIdx.y * 32;
    const int n0 = blockIdx.x * 32;
    const float* xb = x + (size_t)bl * C_ * N_;
    ushort_t* xhb = xh + (size_t)bl * N_ * C_;
    ushort_t* xlb = xl + (size_t)bl * N_ * C_;
    const int tx = threadIdx.x & 31, ty = threadIdx.x >> 5;
    #pragma unroll
    for (int r = 0; r < 4; ++r)
        t[ty + r * 8][tx] = xb[(size_t)(c0 + ty + r * 8) * N_ + n0 + tx];
    __syncthreads();
    #pragma unroll
    for (int r = 0; r < 4; ++r) {
        float v = t[tx][ty + r * 8];
        size_t o = (size_t)(n0 + ty + r * 8) * C_ + c0 + tx;
        split_write(v, xhb, xlb, o);
    }
}

// ===========================================================================
// 8-phase 256x256 GEMM machinery.
// Block: 512 thr = 8 waves (2 row-waves x 4 col-waves); wave tile 128x64.
// BK=32; LDS tiles [128 rows][32 k] bf16, 16B-chunk XOR swizzle
//   chunk' = chunk ^ ((row>>1)&3)
// staged via global_load_lds with PRE-SWIZZLED per-lane source addresses
// (linear LDS dest; same involution on the ds_read side).
// Per K-step: 4 phases; phase reads A-frags (2) [+ all B frags in phase 0],
// issues next-step half-tiles (phases 0-1), raw s_barrier / lgkmcnt(0) /
// setprio around the MFMA cluster; vmcnt(0) once per step at phase 3.
// ===========================================================================

// ---------------------------------------------------------------------------
// G1: y[o][n] = sum_c F[o][c] x[c][n],  o in [0,1024)
//     o<512  -> t: written transposed+split  tT[n][o]
//     o>=512 -> v: written natural+split     v[c][m]
// ---------------------------------------------------------------------------
__global__ __launch_bounds__(512, 2) void g1_mfma(const ushort_t* __restrict__ Fh_,
                                                  const ushort_t* __restrict__ Fl_,
                                                  const ushort_t* __restrict__ xTh_,
                                                  const ushort_t* __restrict__ xTl_,
                                                  ushort_t* __restrict__ tTh_,
                                                  ushort_t* __restrict__ tTl_,
                                                  ushort_t* __restrict__ vh_,
                                                  ushort_t* __restrict__ vl_) {
    __shared__ ushort_t lds[2][4][2][4096];   // [buf][plane Ah,Al,Bh,Bl][half][8KB]
    const int bl = blockIdx.z;
    const int n0 = blockIdx.x * 256;
    const int m0 = blockIdx.y * 256;
    const char* Ah = (const char*)Fh_;
    const char* Al = (const char*)Fl_;
    const char* Bh = (const char*)(xTh_ + (size_t)bl * N_ * C_);
    const char* Bl = (const char*)(xTl_ + (size_t)bl * N_ * C_);

    const int tid = threadIdx.x;
    const int lane = tid & 63, wid = tid >> 6;
    const int wr = wid >> 2, wc = wid & 3;
    const int lr = lane & 15, g = lane >> 4;
    const int cswz = g ^ ((lr >> 1) & 3);
    const int offA = lr * 32 + cswz * 8;
    const int offB = ((wc & 1) * 64 + lr) * 32 + cswz * 8;
    const int srow = tid >> 2;
    const int toff = srow * 1024 + (((tid & 3) ^ ((srow >> 1) & 3)) << 4);
    const int ldst = wid * 512;

    f32x4 acc[8][4] = {};

#define G1_ISSUE_A(buf, kb) \
    gld16(Ah + (size_t)(m0)       * 1024 + (kb) + toff, &lds[buf][0][0][ldst]); \
    gld16(Ah + (size_t)(m0 + 128) * 1024 + (kb) + toff, &lds[buf][0][1][ldst]); \
    gld16(Al + (size_t)(m0)       * 1024 + (kb) + toff, &lds[buf][1][0][ldst]); \
    gld16(Al + (size_t)(m0 + 128) * 1024 + (kb) + toff, &lds[buf][1][1][ldst]);
#define G1_ISSUE_B(buf, kb) \
    gld16(Bh + (size_t)(n0)       * 1024 + (kb) + toff, &lds[buf][2][0][ldst]); \
    gld16(Bh + (size_t)(n0 + 128) * 1024 + (kb) + toff, &lds[buf][2][1][ldst]); \
    gld16(Bl + (size_t)(n0)       * 1024 + (kb) + toff, &lds[buf][3][0][ldst]); \
    gld16(Bl + (size_t)(n0 + 128) * 1024 + (kb) + toff, &lds[buf][3][1][ldst]);

    G1_ISSUE_A(0, 0);
    G1_ISSUE_B(0, 0);
    asm volatile("s_waitcnt vmcnt(0)" ::: "memory");
    __builtin_amdgcn_s_barrier();

    bf16x8 bfh[4], bfl[4];
    for (int t = 0; t < 16; ++t) {
        const int cur = t & 1, nxt = cur ^ 1;
        const bool pf = (t < 15);
        const int nk = (t + 1) * 64;
        #pragma unroll
        for (int p = 0; p < 4; ++p) {
            if (p == 0) {
                #pragma unroll
                for (int j = 0; j < 4; ++j) {
                    bfh[j] = *(const bf16x8*)&lds[cur][2][wc >> 1][j * 512 + offB];
                    bfl[j] = *(const bf16x8*)&lds[cur][3][wc >> 1][j * 512 + offB];
                }
            }
            bf16x8 ah0 = *(const bf16x8*)&lds[cur][0][wr][(p * 2 + 0) * 512 + offA];
            bf16x8 al0 = *(const bf16x8*)&lds[cur][1][wr][(p * 2 + 0) * 512 + offA];
            bf16x8 ah1 = *(const bf16x8*)&lds[cur][0][wr][(p * 2 + 1) * 512 + offA];
            bf16x8 al1 = *(const bf16x8*)&lds[cur][1][wr][(p * 2 + 1) * 512 + offA];
            if (pf && p == 0) { G1_ISSUE_A(nxt, nk); }
            if (pf && p == 1) { G1_ISSUE_B(nxt, nk); }
            __builtin_amdgcn_s_barrier();
            asm volatile("s_waitcnt lgkmcnt(0)" ::: "memory");
            __builtin_amdgcn_s_setprio(1);
            #pragma unroll
            for (int j = 0; j < 4; ++j) {
                acc[p*2+0][j] = __builtin_amdgcn_mfma_f32_16x16x32_bf16(ah0, bfh[j], acc[p*2+0][j], 0,0,0);
                acc[p*2+0][j] = __builtin_amdgcn_mfma_f32_16x16x32_bf16(ah0, bfl[j], acc[p*2+0][j], 0,0,0);
                acc[p*2+0][j] = __builtin_amdgcn_mfma_f32_16x16x32_bf16(al0, bfh[j], acc[p*2+0][j], 0,0,0);
                acc[p*2+1][j] = __builtin_amdgcn_mfma_f32_16x16x32_bf16(ah1, bfh[j], acc[p*2+1][j], 0,0,0);
                acc[p*2+1][j] = __builtin_amdgcn_mfma_f32_16x16x32_bf16(ah1, bfl[j], acc[p*2+1][j], 0,0,0);
                acc[p*2+1][j] = __builtin_amdgcn_mfma_f32_16x16x32_bf16(al1, bfh[j], acc[p*2+1][j], 0,0,0);
            }
            __builtin_amdgcn_s_setprio(0);
            if (p == 3) asm volatile("s_waitcnt vmcnt(0)" ::: "memory");
            __builtin_amdgcn_s_barrier();
        }
    }
#undef G1_ISSUE_A
#undef G1_ISSUE_B

    if (m0 < 512) {
        // t region: write transposed split planes tT[n][o], stride C_
        ushort_t* th = tTh_ + (size_t)bl * N_ * C_;
        ushort_t* tl = tTl_ + (size_t)bl * N_ * C_;
        #pragma unroll
        for (int i = 0; i < 8; ++i) {
            int ob = m0 + wr * 128 + i * 16 + g * 4;
            #pragma unroll
            for (int j = 0; j < 4; ++j) {
                int n = n0 + wc * 64 + j * 16 + lr;
                ushort4 h4, l4;
                ushort_t hb;
                float v0 = acc[i][j][0], v1 = acc[i][j][1], v2 = acc[i][j][2], v3 = acc[i][j][3];
                hb = f2bf(v0); h4.x = hb; l4.x = f2bf(v0 - bf2f(hb));
                hb = f2bf(v1); h4.y = hb; l4.y = f2bf(v1 - bf2f(hb));
                hb = f2bf(v2); h4.z = hb; l4.z = f2bf(v2 - bf2f(hb));
                hb = f2bf(v3); h4.w = hb; l4.w = f2bf(v3 - bf2f(hb));
                *reinterpret_cast<ushort4*>(&th[(size_t)n * C_ + ob]) = h4;
                *reinterpret_cast<ushort4*>(&tl[(size_t)n * C_ + ob]) = l4;
            }
        }
    } else {
        // v region: natural split planes v[c][m], stride N_
        ushort_t* vh = vh_ + (size_t)bl * C_ * N_;
        ushort_t* vl = vl_ + (size_t)bl * C_ * N_;
        #pragma unroll
        for (int i = 0; i < 8; ++i) {
            int cb = m0 - 512 + wr * 128 + i * 16 + g * 4;
            #pragma unroll
            for (int j = 0; j < 4; ++j) {
                int m = n0 + wc * 64 + j * 16 + lr;
                #pragma unroll
                for (int r = 0; r < 4; ++r) {
                    float v = acc[i][j][r];
                    ushort_t hb = f2bf(v);
                    vh[(size_t)(cb + r) * N_ + m] = hb;
                    vl[(size_t)(cb + r) * N_ + m] = f2bf(v - bf2f(hb));
                }
            }
        }
    }
}

// ---------------------------------------------------------------------------
// G2: S[n][m] = sum_{k<1024} A[n][k]*B[m][k];  A=[xT|rT], B=[tT|xT] (split)
// ---------------------------------------------------------------------------
__global__ __launch_bounds__(512, 2) void g2_mfma(const ushort_t* __restrict__ xTh_,
                                                  const ushort_t* __restrict__ xTl_,
                                                  const ushort_t* __restrict__ rTh_,
                                                  const ushort_t* __restrict__ rTl_,
                                                  const ushort_t* __restrict__ tTh_,
                                                  const ushort_t* __restrict__ tTl_,
                                                  float* __restrict__ S) {
    __shared__ ushort_t lds[2][4][2][4096];
    const int bl = blockIdx.z;
    const int m0 = blockIdx.x * 256;
    const int n0 = blockIdx.y * 256;
    const char* xh = (const char*)(xTh_ + (size_t)bl * N_ * C_);
    const char* xl = (const char*)(xTl_ + (size_t)bl * N_ * C_);
    const char* th = (const char*)(tTh_ + (size_t)bl * N_ * C_);
    const char* tl = (const char*)(tTl_ + (size_t)bl * N_ * C_);
    const char* rh = (const char*)rTh_;
    const char* rl = (const char*)rTl_;

    const int tid = threadIdx.x;
    const int lane = tid & 63, wid = tid >> 6;
    const int wr = wid >> 2, wc = wid & 3;
    const int lr = lane & 15, g = lane >> 4;
    const int cswz = g ^ ((lr >> 1) & 3);
    const int offA = lr * 32 + cswz * 8;
    const int offB = ((wc & 1) * 64 + lr) * 32 + cswz * 8;
    const int srow = tid >> 2;
    const int toff = srow * 1024 + (((tid & 3) ^ ((srow >> 1) & 3)) << 4);
    const int ldst = wid * 512;

    f32x4 acc[8][4] = {};

#define G2_SRC(s, vAh, vAl, vBh, vBl, vk) \
    const char *vAh, *vAl, *vBh, *vBl; int vk; \
    if ((s) < 16) { vAh = xh; vAl = xl; vBh = th; vBl = tl; vk = (s) * 64; } \
    else          { vAh = rh; vAl = rl; vBh = xh; vBl = xl; vk = ((s) - 16) * 64; }
#define G2_ISSUE_A(buf, vAh, vAl, vk) \
    gld16(vAh + (size_t)(n0)       * 1024 + (vk) + toff, &lds[buf][0][0][ldst]); \
    gld16(vAh + (size_t)(n0 + 128) * 1024 + (vk) + toff, &lds[buf][0][1][ldst]); \
    gld16(vAl + (size_t)(n0)       * 1024 + (vk) + toff, &lds[buf][1][0][ldst]); \
    gld16(vAl + (size_t)(n0 + 128) * 1024 + (vk) + toff, &lds[buf][1][1][ldst]);
#define G2_ISSUE_B(buf, vBh, vBl, vk) \
    gld16(vBh + (size_t)(m0)       * 1024 + (vk) + toff, &lds[buf][2][0][ldst]); \
    gld16(vBh + (size_t)(m0 + 128) * 1024 + (vk) + toff, &lds[buf][2][1][ldst]); \
    gld16(vBl + (size_t)(m0)       * 1024 + (vk) + toff, &lds[buf][3][0][ldst]); \
    gld16(vBl + (size_t)(m0 + 128) * 1024 + (vk) + toff, &lds[buf][3][1][ldst]);

    {
        G2_SRC(0, pAh, pAl, pBh, pBl, pk);
        G2_ISSUE_A(0, pAh, pAl, pk);
        G2_ISSUE_B(0, pBh, pBl, pk);
        asm volatile("s_waitcnt vmcnt(0)" ::: "memory");
        __builtin_amdgcn_s_barrier();
    }

    bf16x8 bfh[4], bfl[4];
    for (int t = 0; t < 32; ++t) {
        const int cur = t & 1, nxt = cur ^ 1;
        const bool pf = (t < 31);
        G2_SRC(t + 1, nAh, nAl, nBh, nBl, nk);
        #pragma unroll
        for (int p = 0; p < 4; ++p) {
            if (p == 0) {
                #pragma unroll
                for (int j = 0; j < 4; ++j) {
                    bfh[j] = *(const bf16x8*)&lds[cur][2][wc >> 1][j * 512 + offB];
                    bfl[j] = *(const bf16x8*)&lds[cur][3][wc >> 1][j * 512 + offB];
                }
            }
            bf16x8 ah0 = *(const bf16x8*)&lds[cur][0][wr][(p * 2 + 0) * 512 + offA];
            bf16x8 al0 = *(const bf16x8*)&lds[cur][1][wr][(p * 2 + 0) * 512 + offA];
            bf16x8 ah1 = *(const bf16x8*)&lds[cur][0][wr][(p * 2 + 1) * 512 + offA];
            bf16x8 al1 = *(const bf16x8*)&lds[cur][1][wr][(p * 2 + 1) * 512 + offA];
            if (pf && p == 0) { G2_ISSUE_A(nxt, nAh, nAl, nk); }
            if (pf && p == 1) { G2_ISSUE_B(nxt, nBh, nBl, nk); }
            __builtin_amdgcn_s_barrier();
            asm volatile("s_waitcnt lgkmcnt(0)" ::: "memory");
            __builtin_amdgcn_s_setprio(1);
            #pragma unroll
            for (int j = 0; j < 4; ++j) {
                acc[p*2+0][j] = __builtin_amdgcn_mfma_f32_16x16x32_bf16(ah0, bfh[j], acc[p*2+0][j], 0,0,0);
                acc[p*2+0][j] = __builtin_amdgcn_mfma_f32_16x16x32_bf16(ah0, bfl[j], acc[p*2+0][j], 0,0,0);
                acc[p*2+0][j] = __builtin_amdgcn_mfma_f32_16x16x32_bf16(al0, bfh[j], acc[p*2+0][j], 0,0,0);
                acc[p*2+1][j] = __builtin_amdgcn_mfma_f32_16x16x32_bf16(ah1, bfh[j], acc[p*2+1][j], 0,0,0);
                acc[p*2+1][j] = __builtin_amdgcn_mfma_f32_16x16x32_bf16(ah1, bfl[j], acc[p*2+1][j], 0,0,0);
                acc[p*2+1][j] = __builtin_amdgcn_mfma_f32_16x16x32_bf16(al1, bfh[j], acc[p*2+1][j], 0,0,0);
            }
            __builtin_amdgcn_s_setprio(0);
            if (p == 3) asm volatile("s_waitcnt vmcnt(0)" ::: "memory");
            __builtin_amdgcn_s_barrier();
        }
    }
#undef G2_SRC
#undef G2_ISSUE_A
#undef G2_ISSUE_B

    float* Sb = S + (size_t)bl * N_ * N_;
    #pragma unroll
    for (int i = 0; i < 8; ++i) {
        int n = n0 + wr * 128 + i * 16 + g * 4;
        #pragma unroll
        for (int j = 0; j < 4; ++j) {
            int m = m0 + wc * 64 + j * 16 + lr;
            #pragma unroll
            for (int r = 0; r < 4; ++r)
                Sb[(size_t)(n + r) * N_ + m] = acc[i][j][r];
        }
    }
}

// ---------------------------------------------------------------------------
// Row softmax (fp32 in) -> P bf16 [n][m]
// ---------------------------------------------------------------------------
__device__ __forceinline__ float waveMax(float v) {
    #pragma unroll
    for (int o = 32; o > 0; o >>= 1) v = fmaxf(v, __shfl_down(v, o));
    return v;
}
__device__ __forceinline__ float waveSum(float v) {
    #pragma unroll
    for (int o = 32; o > 0; o >>= 1) v += __shfl_down(v, o);
    return v;
}

__global__ __launch_bounds__(256) void softmax_bf16(const float* __restrict__ S,
                                                    ushort_t* __restrict__ P) {
    const float* Sr = S + (size_t)blockIdx.x * N_;
    ushort_t* Pr = P + (size_t)blockIdx.x * N_;
    const int tid = threadIdx.x;
    float4 v = reinterpret_cast<const float4*>(Sr)[tid];
    __shared__ float redm[4];
    __shared__ float reds[4];
    const int wave = tid >> 6, lane = tid & 63;

    float m = fmaxf(fmaxf(v.x, v.y), fmaxf(v.z, v.w));
    m = waveMax(m);
    if (lane == 0) redm[wave] = m;
    __syncthreads();
    m = fmaxf(fmaxf(redm[0], redm[1]), fmaxf(redm[2], redm[3]));

    v.x = __expf(v.x - m); v.y = __expf(v.y - m);
    v.z = __expf(v.z - m); v.w = __expf(v.w - m);
    float s = v.x + v.y + v.z + v.w;
    s = waveSum(s);
    if (lane == 0) reds[wave] = s;
    __syncthreads();
    s = reds[0] + reds[1] + reds[2] + reds[3];
    const float inv = 1.0f / s;
    ushort4 p;
    p.x = f2bf(v.x * inv); p.y = f2bf(v.y * inv);
    p.z = f2bf(v.z * inv); p.w = f2bf(v.w * inv);
    reinterpret_cast<ushort4*>(Pr)[tid] = p;
}

// ---------------------------------------------------------------------------
// G4: out[c][n] = sum_m v[c][m] P[n][m]   (A = v hi/lo, B = P single; 2 MFMA)
// ---------------------------------------------------------------------------
__global__ __launch_bounds__(512, 2) void g4_mfma(const ushort_t* __restrict__ vh_,
                                                  const ushort_t* __restrict__ vl_,
                                                  const ushort_t* __restrict__ P_,
                                                  float* __restrict__ out) {
    __shared__ ushort_t lds[2][3][2][4096];   // planes: Ah, Al, B
    const int bl = blockIdx.z;
    const int n0 = blockIdx.x * 256;
    const int c0 = blockIdx.y * 256;
    const char* Ah = (const char*)(vh_ + (size_t)bl * C_ * N_);
    const char* Al = (const char*)(vl_ + (size_t)bl * C_ * N_);
    const char* Bp = (const char*)(P_ + (size_t)bl * N_ * N_);

    const int tid = threadIdx.x;
    const int lane = tid & 63, wid = tid >> 6;
    const int wr = wid >> 2, wc = wid & 3;
    const int lr = lane & 15, g = lane >> 4;
    const int cswz = g ^ ((lr >> 1) & 3);
    const int offA = lr * 32 + cswz * 8;
    const int offB = ((wc & 1) * 64 + lr) * 32 + cswz * 8;
    const int srow = tid >> 2;
    const int toff = srow * 2048 + (((tid & 3) ^ ((srow >> 1) & 3)) << 4);
    const int ldst = wid * 512;

    f32x4 acc[8][4] = {};

#define G4_ISSUE_A(buf, kb) \
    gld16(Ah + (size_t)(c0)       * 2048 + (kb) + toff, &lds[buf][0][0][ldst]); \
    gld16(Ah + (size_t)(c0 + 128) * 2048 + (kb) + toff, &lds[buf][0][1][ldst]); \
    gld16(Al + (size_t)(c0)       * 2048 + (kb) + toff, &lds[buf][1][0][ldst]); \
    gld16(Al + (size_t)(c0 + 128) * 2048 + (kb) + toff, &lds[buf][1][1][ldst]);
#define G4_ISSUE_B(buf, kb) \
    gld16(Bp + (size_t)(n0)       * 2048 + (kb) + toff, &lds[buf][2][0][ldst]); \
    gld16(Bp + (size_t)(n0 + 128) * 2048 + (kb) + toff, &lds[buf][2][1][ldst]);

    G4_ISSUE_A(0, 0);
    G4_ISSUE_B(0, 0);
    asm volatile("s_waitcnt vmcnt(0)" ::: "memory");
    __builtin_amdgcn_s_barrier();

    bf16x8 bf[4];
    for (int t = 0; t < 32; ++t) {
        const int cur = t & 1, nxt = cur ^ 1;
        const bool pf = (t < 31);
        const int nk = (t + 1) * 64;
        #pragma unroll
        for (int p = 0; p < 4; ++p) {
            if (p == 0) {
                #pragma unroll
                for (int j = 0; j < 4; ++j)
                    bf[j] = *(const bf16x8*)&lds[cur][2][wc >> 1][j * 512 + offB];
            }
            bf16x8 ah0 = *(const bf16x8*)&lds[cur][0][wr][(p * 2 + 0) * 512 + offA];
            bf16x8 al0 = *(const bf16x8*)&lds[cur][1][wr][(p * 2 + 0) * 512 + offA];
            bf16x8 ah1 = *(const bf16x8*)&lds[cur][0][wr][(p * 2 + 1) * 512 + offA];
            bf16x8 al1 = *(const bf16x8*)&lds[cur][1][wr][(p * 2 + 1) * 512 + offA];
            if (pf && p == 0) { G4_ISSUE_A(nxt, nk); }
            if (pf && p == 1) { G4_ISSUE_B(nxt, nk); }
            __builtin_amdgcn_s_barrier();
            asm volatile("s_waitcnt lgkmcnt(0)" ::: "memory");
            __builtin_amdgcn_s_setprio(1);
            #pragma unroll
            for (int j = 0; j < 4; ++j) {
                acc[p*2+0][j] = __builtin_amdgcn_mfma_f32_16x16x32_bf16(ah0, bf[j], acc[p*2+0][j], 0,0,0);
                acc[p*2+0][j] = __builtin_amdgcn_mfma_f32_16x16x32_bf16(al0, bf[j], acc[p*2+0][j], 0,0,0);
                acc[p*2+1][j] = __builtin_amdgcn_mfma_f32_16x16x32_bf16(ah1, bf[j], acc[p*2+1][j], 0,0,0);
                acc[p*2+1][j] = __builtin_amdgcn_mfma_f32_16x16x32_bf16(al1, bf[j], acc[p*2+1][j], 0,0,0);
            }
            __builtin_amdgcn_s_setprio(0);
            if (p == 3) asm volatile("s_waitcnt vmcnt(0)" ::: "memory");
            __builtin_amdgcn_s_barrier();
        }
    }
#undef G4_ISSUE_A
#undef G4_ISSUE_B

    float* ob = out + (size_t)bl * C_ * N_;
    #pragma unroll
    for (int i = 0; i < 8; ++i) {
        int c = c0 + wr * 128 + i * 16 + g * 4;
        #pragma unroll
        for (int j = 0; j < 4; ++j) {
            int n = n0 + wc * 64 + j * 16 + lr;
            #pragma unroll
            for (int r = 0; r < 4; ++r)
                ob[(size_t)(c + r) * N_ + n] = acc[i][j][r];
        }
    }
}

// ---------------------------------------------------------------------------
extern "C" void kernel_launch(void* const* d_in, const int* in_sizes, int n_in,
                              void* d_out, int out_size, void* d_ws, size_t ws_size,
                              hipStream_t stream) {
    const float* x     = (const float*)d_in[0];
    const float* Wm    = (const float*)d_in[1];
    const float* rel_h = (const float*)d_in[2];
    const float* rel_w = (const float*)d_in[3];
    float* out = (float*)d_out;

    // Workspace:
    //   persist: pos f32 2MB, Mtmp f32 1MB, rtmp f32 2MB,
    //            Fh/Fl 1MB each, rTh/rTl 1MB each                 = 9 MiB
    //   per batch: xT 2x1MB, tT 2x1MB, v 2x1MB, S f32 4MB, P 2MB  = 12 MiB
    const size_t posB  = (size_t)C_ * N_ * 4;
    const size_t MtB   = (size_t)C_ * C_ * 4;
    const size_t rtB   = (size_t)C_ * N_ * 4;
    const size_t fplB  = (size_t)1024 * C_ * 2;
    const size_t rtplB = (size_t)N_ * C_ * 2;
    const size_t xtB   = (size_t)N_ * C_ * 2;
    const size_t ttB   = (size_t)N_ * C_ * 2;
    const size_t vplB  = (size_t)C_ * N_ * 2;
    const size_t sB    = (size_t)N_ * N_ * 4;
    const size_t pB    = (size_t)N_ * N_ * 2;
    const size_t per_batch = 2 * xtB + 2 * ttB + 2 * vplB + sB + pB;
    const size_t persist   = posB + MtB + rtB + 2 * fplB + 2 * rtplB;

    size_t rem = (ws_size > persist) ? (ws_size - persist) : 0;
    int chunkB = (int)(rem / per_batch);
    if (chunkB < 1)  chunkB = 1;
    if (chunkB > B_) chunkB = B_;

    char* p = (char*)d_ws;
    float*    pos  = (float*)p;    p += posB;
    float*    Mtmp = (float*)p;    p += MtB;
    float*    rtmp = (float*)p;    p += rtB;
    ushort_t* Fh   = (ushort_t*)p; p += fplB;
    ushort_t* Fl   = (ushort_t*)p; p += fplB;
    ushort_t* rTh  = (ushort_t*)p; p += rtplB;
    ushort_t* rTl  = (ushort_t*)p; p += rtplB;
    ushort_t* xTh  = (ushort_t*)p; p += (size_t)chunkB * xtB;
    ushort_t* xTl  = (ushort_t*)p; p += (size_t)chunkB * xtB;
    ushort_t* tTh  = (ushort_t*)p; p += (size_t)chunkB * ttB;
    ushort_t* tTl  = (ushort_t*)p; p += (size_t)chunkB * ttB;
    ushort_t* vh   = (ushort_t*)p; p += (size_t)chunkB * vplB;
    ushort_t* vl   = (ushort_t*)p; p += (size_t)chunkB * vplB;
    float*    S    = (float*)p;    p += (size_t)chunkB * sB;
    ushort_t* P    = (ushort_t*)p; p += (size_t)chunkB * pB;

    dim3 blk16(16, 16);
    // ---- one-time prep: pos, M = Wq^T Wk, r = Wq^T pos, F=[M;Wv], rT
    pos_kernel<<<(C_ * N_ + 255) / 256, 256, 0, stream>>>(rel_h, rel_w, pos);
    mmT_f32<<<dim3(C_ / 64, C_ / 64), blk16, 0, stream>>>(Wm, C_, Wm + (size_t)C_ * C_, C_,
                                                          Mtmp, C_, C_);
    mmT_f32<<<dim3(N_ / 64, C_ / 64), blk16, 0, stream>>>(Wm, C_, pos, N_, rtmp, N_, C_);
    f_split<<<(1024 * C_ + 255) / 256, 256, 0, stream>>>(Mtmp, Wm, Fh, Fl);
    xT_split<<<dim3(N_ / 32, C_ / 32, 1), 256, 0, stream>>>(rtmp, rTh, rTl);

    for (int b0 = 0; b0 < B_; b0 += chunkB) {
        int nb = (b0 + chunkB <= B_) ? chunkB : (B_ - b0);
        const float* x_b   = x   + (size_t)b0 * C_ * N_;
        float*       out_b = out + (size_t)b0 * C_ * N_;
        xT_split<<<dim3(N_ / 32, C_ / 32, nb), 256, 0, stream>>>(x_b, xTh, xTl);
        g1_mfma<<<dim3(4, 4, nb), 512, 0, stream>>>(Fh, Fl, xTh, xTl, tTh, tTl, vh, vl);
        g2_mfma<<<dim3(4, 4, nb), 512, 0, stream>>>(xTh, xTl, rTh, rTl, tTh, tTl, S);
        softmax_bf16<<<nb * N_, 256, 0, stream>>>(S, P);
        g4_mfma<<<dim3(4, 2, nb), 512, 0, stream>>>(vh, vl, P, out_b);
    }
}